// Round 1
// baseline (6894.524 us; speedup 1.0000x reference)
//
#include <hip/hip_runtime.h>
#include <math.h>

#define N 1024
#define NN (N*N)

// ======================= init =======================
__global__ void init_kernel(double* scores) {
  int t = threadIdx.x;
  if (t < 16) scores[t] = 0.0;
}

// ======================= copy x -> LU workspace =======================
__global__ __launch_bounds__(256) void copy_kernel(const float4* __restrict__ src,
                                                   float4* __restrict__ dst) {
  int i = blockIdx.x * 256 + threadIdx.x;   // grid sized exactly: 16M floats / 4
  dst[i] = src[i];
}

// ======================= LU panel factorization (width 32) =======================
// One block per matrix. Panel rows c0..N-1, cols c0..c0+31 held in LDS col-major
// with stride 1025 (conflict-free for both column scans and row updates).
// Partial pivoting within the panel; pivots recorded globally; row swaps applied
// only to panel columns here (left columns irrelevant for |det|, trailing columns
// swapped by swap_trsm_kernel). Accumulates sum(log|u_jj|) into scores[m] (fp64).
__global__ __launch_bounds__(256) void panel_kernel(float* __restrict__ lu,
                                                    int* __restrict__ ipiv,
                                                    double* __restrict__ scores,
                                                    int c0) {
  __shared__ float sh[32 * 1025];
  __shared__ float redv[4];
  __shared__ int   redi[4];
  __shared__ int   piv;
  const int m = blockIdx.x;
  float* A = lu + (size_t)m * NN;
  const int R = N - c0;
  const int tid = threadIdx.x;

  for (int idx = tid; idx < (R << 5); idx += 256) {
    int r = idx >> 5, j = idx & 31;
    sh[j * 1025 + r] = A[(size_t)(c0 + r) * N + (c0 + j)];
  }
  __syncthreads();

  double logsum = 0.0;
  for (int j = 0; j < 32; ++j) {
    // ---- pivot search: max |col j| over rows j..R-1 ----
    float best = -1.0f; int bi = j;
    for (int r = j + tid; r < R; r += 256) {
      float v = fabsf(sh[j * 1025 + r]);
      if (v > best) { best = v; bi = r; }
    }
    #pragma unroll
    for (int off = 32; off > 0; off >>= 1) {
      float ob = __shfl_down(best, off);
      int   oi = __shfl_down(bi, off);
      if (ob > best || (ob == best && oi < bi)) { best = ob; bi = oi; }
    }
    if ((tid & 63) == 0) { redv[tid >> 6] = best; redi[tid >> 6] = bi; }
    __syncthreads();
    if (tid == 0) {
      float b0 = redv[0]; int i0 = redi[0];
      for (int w = 1; w < 4; ++w)
        if (redv[w] > b0 || (redv[w] == b0 && redi[w] < i0)) { b0 = redv[w]; i0 = redi[w]; }
      piv = i0;
      ipiv[m * 32 + j] = c0 + i0;
    }
    __syncthreads();
    int p = piv;
    if (p != j && tid < 32) {   // swap rows j,p across the 32 panel cols
      float a = sh[tid * 1025 + j], b = sh[tid * 1025 + p];
      sh[tid * 1025 + j] = b; sh[tid * 1025 + p] = a;
    }
    __syncthreads();
    float ujj = sh[j * 1025 + j];
    if (tid == 0) logsum += log(fabs((double)ujj));
    float rujj = 1.0f / ujj;
    float urow[32];
    #pragma unroll
    for (int jj = 0; jj < 32; ++jj) urow[jj] = sh[jj * 1025 + j];
    for (int r = j + 1 + tid; r < R; r += 256) {
      float l = sh[j * 1025 + r] * rujj;
      sh[j * 1025 + r] = l;
      #pragma unroll
      for (int jj = 0; jj < 32; ++jj)
        if (jj > j) sh[jj * 1025 + r] -= l * urow[jj];
    }
    __syncthreads();
  }

  for (int idx = tid; idx < (R << 5); idx += 256) {
    int r = idx >> 5, j = idx & 31;
    A[(size_t)(c0 + r) * N + (c0 + j)] = sh[j * 1025 + r];
  }
  if (tid == 0) atomicAdd(&scores[m], logsum);
}

// ======================= apply pivots to trailing cols + TRSM (U12 = L11^-1 A12) ===
__global__ __launch_bounds__(256) void swap_trsm_kernel(float* __restrict__ lu,
                                                        const int* __restrict__ ipiv,
                                                        int c0, int cpb) {
  const int m  = blockIdx.x / cpb;
  const int cb = blockIdx.x % cpb;
  const int col = c0 + 32 + cb * 256 + threadIdx.x;
  float* A = lu + (size_t)m * NN;
  __shared__ float L[32][33];
  for (int idx = threadIdx.x; idx < 1024; idx += 256) {
    int i = idx >> 5, k = idx & 31;
    L[i][k] = A[(size_t)(c0 + i) * N + (c0 + k)];
  }
  __syncthreads();
  const bool act = col < N;
  #pragma unroll 1
  for (int j = 0; j < 32; ++j) {
    int p  = ipiv[m * 32 + j];
    int jg = c0 + j;
    if (p != jg && act) {
      float a = A[(size_t)jg * N + col];
      float b = A[(size_t)p  * N + col];
      A[(size_t)jg * N + col] = b;
      A[(size_t)p  * N + col] = a;
    }
  }
  if (act) {
    float u[32];
    #pragma unroll
    for (int i = 0; i < 32; ++i) {
      float a = A[(size_t)(c0 + i) * N + col];
      #pragma unroll
      for (int k = 0; k < i; ++k) a -= L[i][k] * u[k];
      u[i] = a;
      A[(size_t)(c0 + i) * N + col] = a;
    }
  }
}

// ======================= trailing update: A22 -= L21 @ U12 (K=32) =======================
__global__ __launch_bounds__(256) void gemm_update_kernel(float* __restrict__ lu, int c0, int nt) {
  const int m  = blockIdx.x / (nt * nt);
  const int t  = blockIdx.x % (nt * nt);
  const int tr = t / nt, tc = t % nt;
  const int r0  = c0 + 32 + tr * 64;
  const int cc0 = c0 + 32 + tc * 64;
  float* A = lu + (size_t)m * NN;
  __shared__ float Ls[64][33];
  __shared__ float Us[32][65];
  for (int idx = threadIdx.x; idx < 64 * 32; idx += 256) {
    int r = idx >> 5, k = idx & 31;
    Ls[r][k] = (r0 + r < N) ? A[(size_t)(r0 + r) * N + (c0 + k)] : 0.0f;
  }
  for (int idx = threadIdx.x; idx < 32 * 64; idx += 256) {
    int k = idx >> 6, c = idx & 63;
    Us[k][c] = (cc0 + c < N) ? A[(size_t)(c0 + k) * N + (cc0 + c)] : 0.0f;
  }
  __syncthreads();
  const int ty = threadIdx.x >> 4, tx = threadIdx.x & 15;
  float acc[4][4] = {};
  #pragma unroll
  for (int k = 0; k < 32; ++k) {
    float a[4], b[4];
    #pragma unroll
    for (int e = 0; e < 4; ++e) { a[e] = Ls[ty * 4 + e][k]; b[e] = Us[k][tx * 4 + e]; }
    #pragma unroll
    for (int i = 0; i < 4; ++i)
      #pragma unroll
      for (int jj = 0; jj < 4; ++jj) acc[i][jj] += a[i] * b[jj];
  }
  #pragma unroll
  for (int i = 0; i < 4; ++i) {
    int r = r0 + ty * 4 + i;
    if (r < N) {
      #pragma unroll
      for (int jj = 0; jj < 4; ++jj) {
        int c = cc0 + tx * 4 + jj;
        if (c < N) A[(size_t)r * N + c] -= acc[i][jj];
      }
    }
  }
}

// ======================= gate + top-k + effective weights =======================
__global__ void select_kernel(const void* __restrict__ flagsraw, const double* __restrict__ scores,
                              const float* __restrict__ w1, const float* __restrict__ b1,
                              const float* __restrict__ w2, const float* __restrict__ b2,
                              int* __restrict__ topidx, float* __restrict__ misc,
                              float* __restrict__ out_tail) {
  if (threadIdx.x != 0 || blockIdx.x != 0) return;
  // robust flag decode: bool bytes / int32 / float32
  const unsigned char* fb = (const unsigned char*)flagsraw;
  bool nonbin = false, off4 = false;
  for (int i = 0; i < 16; ++i) {
    if (fb[i] > 1) nonbin = true;
    if ((i & 3) && fb[i]) off4 = true;
  }
  int f[16]; int nact = 0;
  for (int i = 0; i < 16; ++i) {
    int v;
    if (nonbin)      v = (((const float*)flagsraw)[i] != 0.0f);
    else if (off4)   v = (fb[i] != 0);
    else             v = (((const int*)flagsraw)[i] != 0);
    f[i] = v; nact += v;
  }
  int gate = (nact >= 4) ? 1 : 0;   // THRESH = 4
  double sc[16];
  for (int i = 0; i < 16; ++i) sc[i] = f[i] ? scores[i] : -1.0e300;
  bool used[16] = {};
  for (int k = 0; k < 8; ++k) {     // descending, ties -> lowest index (lax.top_k)
    int bi = -1; double bv = 0.0;
    for (int i = 0; i < 16; ++i)
      if (!used[i] && (bi < 0 || sc[i] > bv)) { bv = sc[i]; bi = i; }
    used[bi] = true;
    topidx[k] = bi;
  }
  // weff = w2 @ w1  (1x10), beff = w2 @ b1 + b2
  for (int c = 0; c < 10; ++c) {
    float s = 0.0f;
    for (int h = 0; h < 32; ++h) s += w2[h] * w1[h * 10 + c];
    misc[c] = s;
  }
  float be = 0.0f;
  for (int h = 0; h < 32; ++h) be += w2[h] * b1[h];
  be += b2[0];
  misc[10] = be;
  ((int*)misc)[12] = gate;
  *out_tail = gate ? 1.0f : 0.0f;   // out_active
}

// ======================= build combined right-hand matrices M0..M2 =======================
__global__ __launch_bounds__(256) void build_m_kernel(const float* __restrict__ x,
                                                      const int* __restrict__ topidx,
                                                      const float* __restrict__ misc,
                                                      float* __restrict__ M) {
  int i = blockIdx.x * 256 + threadIdx.x;   // 262144 float4 positions
  const float4* T1 = (const float4*)(x + (size_t)topidx[1] * NN);
  const float4* T2 = (const float4*)(x + (size_t)topidx[2] * NN);
  const float4* T3 = (const float4*)(x + (size_t)topidx[3] * NN);
  float w0 = misc[0], w1_ = misc[1], w2_ = misc[2], w3_ = misc[3], w4_ = misc[4], w5_ = misc[5];
  float4 t1 = T1[i], t2 = T2[i], t3 = T3[i];
  float4 m0, m1, m2;
  m0.x = w0 * t1.x + w1_ * t2.x + w2_ * t3.x;
  m0.y = w0 * t1.y + w1_ * t2.y + w2_ * t3.y;
  m0.z = w0 * t1.z + w1_ * t2.z + w2_ * t3.z;
  m0.w = w0 * t1.w + w1_ * t2.w + w2_ * t3.w;
  m1.x = w3_ * t2.x + w4_ * t3.x;
  m1.y = w3_ * t2.y + w4_ * t3.y;
  m1.z = w3_ * t2.z + w4_ * t3.z;
  m1.w = w3_ * t2.w + w4_ * t3.w;
  m2.x = w5_ * t3.x;
  m2.y = w5_ * t3.y;
  m2.z = w5_ * t3.z;
  m2.w = w5_ * t3.w;
  ((float4*)M)[i] = m0;
  ((float4*)(M + NN))[i] = m1;
  ((float4*)(M + 2 * (size_t)NN))[i] = m2;
}

// ======================= preserve channels + bias (output base) =======================
__global__ __launch_bounds__(256) void preserve_kernel(const float* __restrict__ x,
                                                       const int* __restrict__ topidx,
                                                       const float* __restrict__ misc,
                                                       float* __restrict__ out) {
  int i = blockIdx.x * 256 + threadIdx.x;
  int gate = ((const int*)misc)[12];
  float4* o = (float4*)out;
  if (!gate) { o[i] = make_float4(0.f, 0.f, 0.f, 0.f); return; }
  float w6 = misc[6], w7 = misc[7], w8 = misc[8], w9 = misc[9], be = misc[10];
  float4 p0 = ((const float4*)(x + (size_t)topidx[4] * NN))[i];
  float4 p1 = ((const float4*)(x + (size_t)topidx[5] * NN))[i];
  float4 p2 = ((const float4*)(x + (size_t)topidx[6] * NN))[i];
  float4 p3 = ((const float4*)(x + (size_t)topidx[7] * NN))[i];
  float4 r;
  r.x = be + w6 * p0.x + w7 * p1.x + w8 * p2.x + w9 * p3.x;
  r.y = be + w6 * p0.y + w7 * p1.y + w8 * p2.y + w9 * p3.y;
  r.z = be + w6 * p0.z + w7 * p1.z + w8 * p2.z + w9 * p3.z;
  r.w = be + w6 * p0.w + w7 * p1.w + w8 * p2.w + w9 * p3.w;
  o[i] = r;
}

// ======================= final: out += T0@M0 + T1@M1 + T2@M2 =======================
__global__ __launch_bounds__(256) void final_gemm_kernel(const float* __restrict__ x,
                                                         const float* __restrict__ M,
                                                         const int* __restrict__ topidx,
                                                         const float* __restrict__ misc,
                                                         float* __restrict__ out) {
  int gate = ((const int*)misc)[12];
  if (!gate) return;
  const int tr = blockIdx.x >> 4, tc = blockIdx.x & 15;
  __shared__ float As[64][33];
  __shared__ float Bs[32][65];
  const int ty = threadIdx.x >> 4, tx = threadIdx.x & 15;
  float acc[4][4] = {};
  for (int mi = 0; mi < 3; ++mi) {
    const float* A = x + (size_t)topidx[mi] * NN;
    const float* B = M + (size_t)mi * NN;
    for (int k0 = 0; k0 < N; k0 += 32) {
      for (int idx = threadIdx.x; idx < 64 * 32; idx += 256) {
        int r = idx >> 5, k = idx & 31;
        As[r][k] = A[(size_t)(tr * 64 + r) * N + k0 + k];
      }
      for (int idx = threadIdx.x; idx < 32 * 64; idx += 256) {
        int k = idx >> 6, c = idx & 63;
        Bs[k][c] = B[(size_t)(k0 + k) * N + tc * 64 + c];
      }
      __syncthreads();
      #pragma unroll
      for (int k = 0; k < 32; ++k) {
        float a[4], b[4];
        #pragma unroll
        for (int e = 0; e < 4; ++e) { a[e] = As[ty * 4 + e][k]; b[e] = Bs[k][tx * 4 + e]; }
        #pragma unroll
        for (int i = 0; i < 4; ++i)
          #pragma unroll
          for (int jj = 0; jj < 4; ++jj) acc[i][jj] += a[i] * b[jj];
      }
      __syncthreads();
    }
  }
  #pragma unroll
  for (int i = 0; i < 4; ++i) {
    size_t r = (size_t)(tr * 64 + ty * 4 + i);
    #pragma unroll
    for (int jj = 0; jj < 4; ++jj) {
      size_t c = (size_t)(tc * 64 + tx * 4 + jj);
      out[r * N + c] += acc[i][jj];
    }
  }
}

// ======================= host =======================
extern "C" void kernel_launch(void* const* d_in, const int* in_sizes, int n_in,
                              void* d_out, int out_size, void* d_ws, size_t ws_size,
                              hipStream_t stream) {
  const float* x   = (const float*)d_in[0];
  const void*  fl  = d_in[1];
  const float* w1  = (const float*)d_in[2];
  const float* b1  = (const float*)d_in[3];
  const float* w2  = (const float*)d_in[4];
  const float* b2  = (const float*)d_in[5];
  float* out = (float*)d_out;

  char* ws = (char*)d_ws;
  float* LU = (float*)ws;                 // 64 MB, dead after LU phase
  float* M  = (float*)ws;                 // 12 MB, reuses LU space (built after LU done)
  size_t tail = (size_t)16 * NN * sizeof(float);   // 67,108,864
  double* scores = (double*)(ws + tail);           // 16 doubles
  int*    ipiv   = (int*)(ws + tail + 256);        // 16*32 ints
  int*    topidx = (int*)(ws + tail + 256 + 2304); // 8 ints
  float*  misc   = (float*)(ws + tail + 256 + 2304 + 256); // weff[10], beff, gate

  init_kernel<<<1, 64, 0, stream>>>(scores);
  copy_kernel<<<16384, 256, 0, stream>>>((const float4*)x, (float4*)LU);

  for (int c0 = 0; c0 < N; c0 += 32) {
    panel_kernel<<<16, 256, 0, stream>>>(LU, ipiv, scores, c0);
    int tcols = N - c0 - 32;
    if (tcols > 0) {
      int cpb = (tcols + 255) / 256;
      swap_trsm_kernel<<<16 * cpb, 256, 0, stream>>>(LU, ipiv, c0, cpb);
      int nt = (tcols + 63) / 64;
      gemm_update_kernel<<<16 * nt * nt, 256, 0, stream>>>(LU, c0, nt);
    }
  }

  select_kernel<<<1, 64, 0, stream>>>(fl, scores, w1, b1, w2, b2, topidx, misc, out + NN);
  build_m_kernel<<<1024, 256, 0, stream>>>(x, topidx, misc, M);
  preserve_kernel<<<1024, 256, 0, stream>>>(x, topidx, misc, out);
  final_gemm_kernel<<<256, 256, 0, stream>>>(x, M, topidx, misc, out);
}

// Round 3
// 6532.211 us; speedup vs baseline: 1.0555x; 1.0555x over previous
//
#include <hip/hip_runtime.h>
#include <math.h>

#define N 1024
#define NN (N*N)

// ======================= init =======================
__global__ void init_kernel(double* scores) {
  int t = threadIdx.x;
  if (t < 16) scores[t] = 0.0;
}

// ======================= copy x -> LU workspace =======================
__global__ __launch_bounds__(256) void copy_kernel(const float4* __restrict__ src,
                                                   float4* __restrict__ dst) {
  int i = blockIdx.x * 256 + threadIdx.x;   // grid sized exactly: 16M floats / 4
  dst[i] = src[i];
}

// ======================= LU panel factorization (width 32) =======================
// VERIFIED round-1 algorithm (physical rows, pivot scan at step start), widened
// to 1024 threads: 1 row/thread in scan and update instead of 4. Reduction
// arrays widened 4 -> 16 waves. Numerics and pivot choice identical to round 1.
__global__ __launch_bounds__(1024) void panel_kernel(float* __restrict__ lu,
                                                     int* __restrict__ ipiv,
                                                     double* __restrict__ scores,
                                                     int c0) {
  __shared__ float sh[32 * 1025];
  __shared__ float redv[16];
  __shared__ int   redi[16];
  __shared__ int   piv;
  const int m = blockIdx.x;
  float* A = lu + (size_t)m * NN;
  const int R = N - c0;
  const int tid = threadIdx.x;

  for (int idx = tid; idx < (R << 5); idx += 1024) {
    int r = idx >> 5, j = idx & 31;
    sh[j * 1025 + r] = A[(size_t)(c0 + r) * N + (c0 + j)];
  }
  __syncthreads();

  double logsum = 0.0;
  for (int j = 0; j < 32; ++j) {
    // ---- pivot search: max |col j| over rows j..R-1 ----
    float best = -1.0f; int bi = j;
    for (int r = j + tid; r < R; r += 1024) {
      float v = fabsf(sh[j * 1025 + r]);
      if (v > best) { best = v; bi = r; }
    }
    #pragma unroll
    for (int off = 32; off > 0; off >>= 1) {
      float ob = __shfl_down(best, off);
      int   oi = __shfl_down(bi, off);
      if (ob > best || (ob == best && oi < bi)) { best = ob; bi = oi; }
    }
    if ((tid & 63) == 0) { redv[tid >> 6] = best; redi[tid >> 6] = bi; }
    __syncthreads();
    if (tid == 0) {
      float b0 = redv[0]; int i0 = redi[0];
      for (int w = 1; w < 16; ++w)
        if (redv[w] > b0 || (redv[w] == b0 && redi[w] < i0)) { b0 = redv[w]; i0 = redi[w]; }
      piv = i0;
      ipiv[m * 32 + j] = c0 + i0;
    }
    __syncthreads();
    int p = piv;
    if (p != j && tid < 32) {   // swap rows j,p across the 32 panel cols
      float a = sh[tid * 1025 + j], b = sh[tid * 1025 + p];
      sh[tid * 1025 + j] = b; sh[tid * 1025 + p] = a;
    }
    __syncthreads();
    float ujj = sh[j * 1025 + j];
    if (tid == 0) logsum += log(fabs((double)ujj));
    float rujj = 1.0f / ujj;
    float urow[32];
    #pragma unroll
    for (int jj = 0; jj < 32; ++jj) urow[jj] = sh[jj * 1025 + j];
    for (int r = j + 1 + tid; r < R; r += 1024) {
      float l = sh[j * 1025 + r] * rujj;
      sh[j * 1025 + r] = l;
      #pragma unroll
      for (int jj = 0; jj < 32; ++jj)
        if (jj > j) sh[jj * 1025 + r] -= l * urow[jj];
    }
    __syncthreads();
  }

  for (int idx = tid; idx < (R << 5); idx += 1024) {
    int r = idx >> 5, j = idx & 31;
    A[(size_t)(c0 + r) * N + (c0 + j)] = sh[j * 1025 + r];
  }
  if (tid == 0) atomicAdd(&scores[m], logsum);
}

// ======================= apply pivots to trailing cols + TRSM (U12 = L11^-1 A12) ===
// VERIFIED round-1 kernel, unchanged.
__global__ __launch_bounds__(256) void swap_trsm_kernel(float* __restrict__ lu,
                                                        const int* __restrict__ ipiv,
                                                        int c0, int cpb) {
  const int m  = blockIdx.x / cpb;
  const int cb = blockIdx.x % cpb;
  const int col = c0 + 32 + cb * 256 + threadIdx.x;
  float* A = lu + (size_t)m * NN;
  __shared__ float L[32][33];
  for (int idx = threadIdx.x; idx < 1024; idx += 256) {
    int i = idx >> 5, k = idx & 31;
    L[i][k] = A[(size_t)(c0 + i) * N + (c0 + k)];
  }
  __syncthreads();
  const bool act = col < N;
  #pragma unroll 1
  for (int j = 0; j < 32; ++j) {
    int p  = ipiv[m * 32 + j];
    int jg = c0 + j;
    if (p != jg && act) {
      float a = A[(size_t)jg * N + col];
      float b = A[(size_t)p  * N + col];
      A[(size_t)jg * N + col] = b;
      A[(size_t)p  * N + col] = a;
    }
  }
  if (act) {
    float u[32];
    #pragma unroll
    for (int i = 0; i < 32; ++i) {
      float a = A[(size_t)(c0 + i) * N + col];
      #pragma unroll
      for (int k = 0; k < 32; ++k)
        if (k < i) a -= L[i][k] * u[k];
      u[i] = a;
      A[(size_t)(c0 + i) * N + col] = a;
    }
  }
}

// ======================= trailing update: A22 -= L21 @ U12 (K=32) =======================
// VERIFIED round-1 kernel, unchanged.
__global__ __launch_bounds__(256) void gemm_update_kernel(float* __restrict__ lu, int c0, int nt) {
  const int m  = blockIdx.x / (nt * nt);
  const int t  = blockIdx.x % (nt * nt);
  const int tr = t / nt, tc = t % nt;
  const int r0  = c0 + 32 + tr * 64;
  const int cc0 = c0 + 32 + tc * 64;
  float* A = lu + (size_t)m * NN;
  __shared__ float Ls[64][33];
  __shared__ float Us[32][65];
  for (int idx = threadIdx.x; idx < 64 * 32; idx += 256) {
    int r = idx >> 5, k = idx & 31;
    Ls[r][k] = (r0 + r < N) ? A[(size_t)(r0 + r) * N + (c0 + k)] : 0.0f;
  }
  for (int idx = threadIdx.x; idx < 32 * 64; idx += 256) {
    int k = idx >> 6, c = idx & 63;
    Us[k][c] = (cc0 + c < N) ? A[(size_t)(c0 + k) * N + (cc0 + c)] : 0.0f;
  }
  __syncthreads();
  const int ty = threadIdx.x >> 4, tx = threadIdx.x & 15;
  float acc[4][4] = {};
  #pragma unroll
  for (int k = 0; k < 32; ++k) {
    float a[4], b[4];
    #pragma unroll
    for (int e = 0; e < 4; ++e) { a[e] = Ls[ty * 4 + e][k]; b[e] = Us[k][tx * 4 + e]; }
    #pragma unroll
    for (int i = 0; i < 4; ++i)
      #pragma unroll
      for (int jj = 0; jj < 4; ++jj) acc[i][jj] += a[i] * b[jj];
  }
  #pragma unroll
  for (int i = 0; i < 4; ++i) {
    int r = r0 + ty * 4 + i;
    if (r < N) {
      #pragma unroll
      for (int jj = 0; jj < 4; ++jj) {
        int c = cc0 + tx * 4 + jj;
        if (c < N) A[(size_t)r * N + c] -= acc[i][jj];
      }
    }
  }
}

// ======================= gate + top-k + effective weights =======================
__global__ void select_kernel(const void* __restrict__ flagsraw, const double* __restrict__ scores,
                              const float* __restrict__ w1, const float* __restrict__ b1,
                              const float* __restrict__ w2, const float* __restrict__ b2,
                              int* __restrict__ topidx, float* __restrict__ misc,
                              float* __restrict__ out_tail) {
  if (threadIdx.x != 0 || blockIdx.x != 0) return;
  const unsigned char* fb = (const unsigned char*)flagsraw;
  bool nonbin = false, off4 = false;
  for (int i = 0; i < 16; ++i) {
    if (fb[i] > 1) nonbin = true;
    if ((i & 3) && fb[i]) off4 = true;
  }
  int f[16]; int nact = 0;
  for (int i = 0; i < 16; ++i) {
    int v;
    if (nonbin)      v = (((const float*)flagsraw)[i] != 0.0f);
    else if (off4)   v = (fb[i] != 0);
    else             v = (((const int*)flagsraw)[i] != 0);
    f[i] = v; nact += v;
  }
  int gate = (nact >= 4) ? 1 : 0;   // THRESH = 4
  double sc[16];
  for (int i = 0; i < 16; ++i) sc[i] = f[i] ? scores[i] : -1.0e300;
  bool used[16] = {};
  for (int k = 0; k < 8; ++k) {     // descending, ties -> lowest index (lax.top_k)
    int bi = -1; double bv = 0.0;
    for (int i = 0; i < 16; ++i)
      if (!used[i] && (bi < 0 || sc[i] > bv)) { bv = sc[i]; bi = i; }
    used[bi] = true;
    topidx[k] = bi;
  }
  for (int cC = 0; cC < 10; ++cC) {
    float s = 0.0f;
    for (int h = 0; h < 32; ++h) s += w2[h] * w1[h * 10 + cC];
    misc[cC] = s;
  }
  float be = 0.0f;
  for (int h = 0; h < 32; ++h) be += w2[h] * b1[h];
  be += b2[0];
  misc[10] = be;
  ((int*)misc)[12] = gate;
  *out_tail = gate ? 1.0f : 0.0f;
}

// ======================= build combined right-hand matrices M0..M2 =======================
__global__ __launch_bounds__(256) void build_m_kernel(const float* __restrict__ x,
                                                      const int* __restrict__ topidx,
                                                      const float* __restrict__ misc,
                                                      float* __restrict__ M) {
  int i = blockIdx.x * 256 + threadIdx.x;   // 262144 float4 positions
  const float4* T1 = (const float4*)(x + (size_t)topidx[1] * NN);
  const float4* T2 = (const float4*)(x + (size_t)topidx[2] * NN);
  const float4* T3 = (const float4*)(x + (size_t)topidx[3] * NN);
  float w0 = misc[0], w1_ = misc[1], w2_ = misc[2], w3_ = misc[3], w4_ = misc[4], w5_ = misc[5];
  float4 t1 = T1[i], t2 = T2[i], t3 = T3[i];
  float4 m0, m1, m2;
  m0.x = w0 * t1.x + w1_ * t2.x + w2_ * t3.x;
  m0.y = w0 * t1.y + w1_ * t2.y + w2_ * t3.y;
  m0.z = w0 * t1.z + w1_ * t2.z + w2_ * t3.z;
  m0.w = w0 * t1.w + w1_ * t2.w + w2_ * t3.w;
  m1.x = w3_ * t2.x + w4_ * t3.x;
  m1.y = w3_ * t2.y + w4_ * t3.y;
  m1.z = w3_ * t2.z + w4_ * t3.z;
  m1.w = w3_ * t2.w + w4_ * t3.w;
  m2.x = w5_ * t3.x;  m2.y = w5_ * t3.y;  m2.z = w5_ * t3.z;  m2.w = w5_ * t3.w;
  ((float4*)M)[i] = m0;
  ((float4*)(M + NN))[i] = m1;
  ((float4*)(M + 2 * (size_t)NN))[i] = m2;
}

// ======================= split-K final GEMM: P[chunk] = A_chunk @ B_chunk ==========
// concat-K view: out = T0@M0 + T1@M1 + T2@M2, K=3072 split into 6 chunks of 512.
__global__ __launch_bounds__(256) void final_gemm_kernel(const float* __restrict__ x,
                                                         const float* __restrict__ M,
                                                         const int* __restrict__ topidx,
                                                         float* __restrict__ P) {
  const int chunk = blockIdx.x >> 8;   // 0..5
  const int t  = blockIdx.x & 255;
  const int tr = t >> 4, tc = t & 15;
  const int mi  = chunk >> 1;
  const int k0b = (chunk & 1) << 9;    // 0 or 512
  const float* A = x + (size_t)topidx[mi] * NN;
  const float* B = M + (size_t)mi * NN;
  __shared__ float As[32][68];   // A^T fragment: As[k][r], float4-aligned stride
  __shared__ float Bs[32][68];
  const int ty = threadIdx.x >> 4, tx = threadIdx.x & 15;
  float acc[4][4] = {};
  for (int k0 = k0b; k0 < k0b + 512; k0 += 32) {
    for (int idx = threadIdx.x; idx < 2048; idx += 256) {
      int r = idx >> 5, k = idx & 31;
      As[k][r] = A[(size_t)(tr * 64 + r) * N + k0 + k];
    }
    for (int idx = threadIdx.x; idx < 2048; idx += 256) {
      int k = idx >> 6, cc = idx & 63;
      Bs[k][cc] = B[(size_t)(k0 + k) * N + tc * 64 + cc];
    }
    __syncthreads();
    #pragma unroll 8
    for (int k = 0; k < 32; ++k) {
      float4 a = *(const float4*)&As[k][ty * 4];
      float4 b = *(const float4*)&Bs[k][tx * 4];
      acc[0][0] += a.x * b.x; acc[0][1] += a.x * b.y; acc[0][2] += a.x * b.z; acc[0][3] += a.x * b.w;
      acc[1][0] += a.y * b.x; acc[1][1] += a.y * b.y; acc[1][2] += a.y * b.z; acc[1][3] += a.y * b.w;
      acc[2][0] += a.z * b.x; acc[2][1] += a.z * b.y; acc[2][2] += a.z * b.z; acc[2][3] += a.z * b.w;
      acc[3][0] += a.w * b.x; acc[3][1] += a.w * b.y; acc[3][2] += a.w * b.z; acc[3][3] += a.w * b.w;
    }
    __syncthreads();
  }
  float* Pc = P + (size_t)chunk * NN;
  #pragma unroll
  for (int i = 0; i < 4; ++i) {
    size_t r = (size_t)(tr * 64 + ty * 4 + i);
    float4 v = make_float4(acc[i][0], acc[i][1], acc[i][2], acc[i][3]);
    *(float4*)&Pc[r * N + tc * 64 + tx * 4] = v;
  }
}

// ======================= reduce partials + preserve channels + bias ================
__global__ __launch_bounds__(256) void reduce_out_kernel(const float* __restrict__ x,
                                                         const float* __restrict__ P,
                                                         const int* __restrict__ topidx,
                                                         const float* __restrict__ misc,
                                                         float* __restrict__ out) {
  int i = blockIdx.x * 256 + threadIdx.x;   // 262144 float4 positions
  int gate = ((const int*)misc)[12];
  float4* o = (float4*)out;
  if (!gate) { o[i] = make_float4(0.f, 0.f, 0.f, 0.f); return; }
  float w6 = misc[6], w7 = misc[7], w8 = misc[8], w9 = misc[9], be = misc[10];
  float4 p0 = ((const float4*)(x + (size_t)topidx[4] * NN))[i];
  float4 p1 = ((const float4*)(x + (size_t)topidx[5] * NN))[i];
  float4 p2 = ((const float4*)(x + (size_t)topidx[6] * NN))[i];
  float4 p3 = ((const float4*)(x + (size_t)topidx[7] * NN))[i];
  float4 r;
  r.x = be + w6 * p0.x + w7 * p1.x + w8 * p2.x + w9 * p3.x;
  r.y = be + w6 * p0.y + w7 * p1.y + w8 * p2.y + w9 * p3.y;
  r.z = be + w6 * p0.z + w7 * p1.z + w8 * p2.z + w9 * p3.z;
  r.w = be + w6 * p0.w + w7 * p1.w + w8 * p2.w + w9 * p3.w;
  #pragma unroll
  for (int cN = 0; cN < 6; ++cN) {
    float4 q = ((const float4*)(P + (size_t)cN * NN))[i];
    r.x += q.x; r.y += q.y; r.z += q.z; r.w += q.w;
  }
  o[i] = r;
}

// ======================= host =======================
extern "C" void kernel_launch(void* const* d_in, const int* in_sizes, int n_in,
                              void* d_out, int out_size, void* d_ws, size_t ws_size,
                              hipStream_t stream) {
  const float* x  = (const float*)d_in[0];
  const void*  fl = d_in[1];
  const float* w1 = (const float*)d_in[2];
  const float* b1 = (const float*)d_in[3];
  const float* w2 = (const float*)d_in[4];
  const float* b2 = (const float*)d_in[5];
  float* out = (float*)d_out;

  char* ws = (char*)d_ws;
  float* LU = (float*)ws;                                // 64 MB (dead after LU phase)
  float* Mm = (float*)ws;                                // 12 MB, reuses LU space
  float* P  = (float*)(ws + (size_t)12 * 1024 * 1024);   // 24 MB partials, inside old LU
  size_t tail = (size_t)16 * NN * sizeof(float);         // 67,108,864 (round-1 layout)
  double* scores = (double*)(ws + tail);                 // 16 doubles
  int*    ipiv   = (int*)(ws + tail + 256);              // 16*32 ints
  int*    topidx = (int*)(ws + tail + 256 + 2304);       // 8 ints
  float*  misc   = (float*)(ws + tail + 256 + 2304 + 256); // weff[10], beff, gate

  init_kernel<<<1, 64, 0, stream>>>(scores);
  copy_kernel<<<16384, 256, 0, stream>>>((const float4*)x, (float4*)LU);

  for (int c0 = 0; c0 < N; c0 += 32) {
    panel_kernel<<<16, 1024, 0, stream>>>(LU, ipiv, scores, c0);
    int tcols = N - c0 - 32;
    if (tcols > 0) {
      int cpb = (tcols + 255) / 256;
      swap_trsm_kernel<<<16 * cpb, 256, 0, stream>>>(LU, ipiv, c0, cpb);
      int nt = (tcols + 63) / 64;
      gemm_update_kernel<<<16 * nt * nt, 256, 0, stream>>>(LU, c0, nt);
    }
  }

  select_kernel<<<1, 64, 0, stream>>>(fl, scores, w1, b1, w2, b2, topidx, misc, out + NN);
  build_m_kernel<<<1024, 256, 0, stream>>>(x, topidx, misc, Mm);
  final_gemm_kernel<<<1536, 256, 0, stream>>>(x, Mm, topidx, P);
  reduce_out_kernel<<<1024, 256, 0, stream>>>(x, P, topidx, misc, out);
}